// Round 12
// baseline (213.768 us; speedup 1.0000x reference)
//
#include <hip/hip_runtime.h>
#include <hip/hip_bf16.h>
#include <math.h>

#define B 8
#define CIN 12
#define CQ 36
#define CP 48               // channel dim padded: 36 data + 2 logL + 10 zero
#define N 4096
#define SCALE 0.28867513459481287f   // 1/sqrt(12)
#define LOG2E 1.4426950408889634f
#define ZSPLIT 8
#define NCHUNK (N / ZSPLIT) // 512
#define NT (NCHUNK / 32)    // 16 tiles per attn WG
#define MSPLIT 2

typedef __attribute__((ext_vector_type(4)))  short bf4_t;
typedef __attribute__((ext_vector_type(8)))  short bf8_t;
typedef __attribute__((ext_vector_type(16))) float f32x16;
typedef __attribute__((ext_vector_type(4)))  float f32x4;

__device__ __forceinline__ unsigned short f2bf(float x) {
  unsigned int u = __float_as_uint(x);
  u += 0x7FFFu + ((u >> 16) & 1u);   // RNE
  return (unsigned short)(u >> 16);
}

#if __has_builtin(__builtin_amdgcn_cvt_pk_bf16_f32)
typedef __attribute__((ext_vector_type(2))) __bf16 bf16x2_t;
__device__ __forceinline__ unsigned pk2bf(float a, float b) {
  bf16x2_t v = __builtin_amdgcn_cvt_pk_bf16_f32(a, b);
  return __builtin_bit_cast(unsigned, v);
}
#else
__device__ __forceinline__ unsigned pk2bf(float a, float b) {
  return (__float_as_uint(a) >> 16) | (__float_as_uint(b) & 0xFFFF0000u);
}
#endif

__device__ __forceinline__ float bf2f(unsigned short u) {
  return __uint_as_float((unsigned)u << 16);
}

__device__ __forceinline__ float exp2fast(float x) {
#if __has_builtin(__builtin_amdgcn_exp2f)
  return __builtin_amdgcn_exp2f(x);
#else
  return exp2f(x);
#endif
}

// 16x16x16 quad-K MFMA (verified R4-R8): A[m=l15][k=q4*4+i], B[k][n=l15],
// D col=l15 row=q4*4+r.
__device__ __forceinline__ f32x4 mfma16(bf4_t a, bf4_t b, f32x4 c) {
#if __has_builtin(__builtin_amdgcn_mfma_f32_16x16x16bf16_1k)
  return __builtin_amdgcn_mfma_f32_16x16x16bf16_1k(a, b, c, 0, 0, 0);
#else
  bf8_t a8 = {a[0], a[1], a[2], a[3], 0, 0, 0, 0};
  bf8_t b8 = {b[0], b[1], b[2], b[3], 0, 0, 0, 0};
  return __builtin_amdgcn_mfma_f32_16x16x32_bf16(a8, b8, c, 0, 0, 0);
#endif
}

// 16B LDS access helpers for 8B-aligned addresses (rows padded to 104/72 B)
__device__ __forceinline__ bf8_t lds_bf8(const unsigned short* p) {
  uint2 a = *(const uint2*)p;
  uint2 b = *(const uint2*)(p + 4);
  uint4 r{a.x, a.y, b.x, b.y};
  return __builtin_bit_cast(bf8_t, r);
}
__device__ __forceinline__ void wlds16(unsigned short* p, uint4 v) {
  *(uint2*)p = uint2{v.x, v.y};
  *(uint2*)(p + 4) = uint2{v.z, v.w};
}

// ---------------- QKV projection + out-bias-init + counter zero ------------
// 1-D grid 768: [0,128) q, [128,256) k(scaled), [256,384) v, [384,768) init.
__global__ __launch_bounds__(256) void qkv_kernel(
    const float* __restrict__ x,
    const float* __restrict__ wq, const float* __restrict__ bq,
    const float* __restrict__ wk, const float* __restrict__ bk,
    const float* __restrict__ wv, const float* __restrict__ bv,
    const float* __restrict__ bo,
    unsigned short* __restrict__ qT, unsigned short* __restrict__ kT,
    unsigned short* __restrict__ vbf, float* __restrict__ out,
    int* __restrict__ cnt) {
  __shared__ float sw[CQ * CIN];
  __shared__ float sb[CQ];
  int bx = blockIdx.x, tid = threadIdx.x;
  int role = bx >> 7; if (role > 3) role = 3;
  if (role == 3) {
    if (bx == 384) { cnt[tid] = 0; cnt[256 + tid] = 0; }  // 512 counters
    int gid = (bx - 384) * 256 + tid;   // over B*CIN*N/4
    int e4 = gid * 4;
    int i = (e4 >> 12) % CIN;
    float bv2 = bo[i];
    *(float4*)(out + e4) = float4{bv2, bv2, bv2, bv2};
    return;
  }
  const float* w  = (role == 0) ? wq : (role == 1) ? wk : wv;
  const float* bb = (role == 0) ? bq : (role == 1) ? bk : bv;
  float scale = (role == 1) ? SCALE * LOG2E : 1.0f;
  for (int e = tid; e < CQ * CIN; e += 256) sw[e] = w[e] * scale;
  if (tid < CQ) sb[tid] = bb[tid] * scale;
  __syncthreads();
  int gid = (bx & 127) * 256 + tid;    // over B*N
  int b = gid >> 12;
  int n = gid & (N - 1);
  float xv[CIN];
#pragma unroll
  for (int i = 0; i < CIN; ++i) xv[i] = x[(b * CIN + i) * N + n];
  if (role == 2) {
#pragma unroll
    for (int o = 0; o < CQ; ++o) {
      float a = sb[o];
#pragma unroll
      for (int i = 0; i < CIN; ++i) a += sw[o * CIN + i] * xv[i];
      vbf[((size_t)b * CP + o) * N + n] = f2bf(a);
    }
  } else {
    __attribute__((aligned(16))) unsigned row[CP / 2];
#pragma unroll
    for (int o = 0; o < CQ; o += 2) {
      float a0 = sb[o], a1 = sb[o + 1];
#pragma unroll
      for (int i = 0; i < CIN; ++i) {
        float xi = xv[i];
        a0 += sw[o * CIN + i] * xi;
        a1 += sw[(o + 1) * CIN + i] * xi;
      }
      row[o / 2] = (unsigned)f2bf(a0) | ((unsigned)f2bf(a1) << 16);
    }
    row[18] = (role == 0) ? 0x3F803F80u : 0u;  // q ch36/37=1.0; k: stats fills
#pragma unroll
    for (int o = 19; o < CP / 2; ++o) row[o] = 0;
    unsigned short* dst = ((role == 0) ? qT : kT) + ((size_t)b * N + n) * CP;
#pragma unroll
    for (int i = 0; i < 6; ++i) *(uint4*)(dst + 8 * i) = *(const uint4*)&row[4 * i];
  }
}

// ---------------- Pass 1: psum + fused logL finalize (last-arriver) --------
__global__ __launch_bounds__(256) void stats_kernel(
    const unsigned short* __restrict__ qT, unsigned short* __restrict__ kT,
    float* __restrict__ psum, int* __restrict__ cnt) {
  __shared__ float red[4][64];
  __shared__ int lastflag;
  int tid = threadIdx.x, lane = tid & 63, wave = tid >> 6;
  int nblk = blockIdx.x, b = blockIdx.y, ms = blockIdx.z;
  int l31 = lane & 31, h = lane >> 5;
  int n0 = nblk * 64;
  size_t bN = (size_t)b * N;
  const unsigned short* krow0 = kT + (bN + n0 + l31) * CP + h * 8;
  const unsigned short* krow1 = krow0 + (size_t)32 * CP;
  bf8_t a0 = *(const bf8_t*)(krow0);
  bf8_t a1 = *(const bf8_t*)(krow0 + 16);
  bf8_t a2 = *(const bf8_t*)(krow0 + 32);
  bf8_t a3 = *(const bf8_t*)(krow1);
  bf8_t a4 = *(const bf8_t*)(krow1 + 16);
  bf8_t a5 = *(const bf8_t*)(krow1 + 32);
  float rs0[16], rs1[16];
#pragma unroll
  for (int r = 0; r < 16; ++r) { rs0[r] = 0.f; rs1[r] = 0.f; }
  const int MW = N / MSPLIT / 4;   // 512 m per wave
  const unsigned short* qbase =
      qT + (bN + ms * (N / MSPLIT) + wave * MW + l31) * CP + h * 8;
#pragma unroll 2
  for (int t = 0; t < MW / 32; ++t) {
    const unsigned short* qrow2 = qbase + (size_t)t * 32 * CP;
    bf8_t b0 = *(const bf8_t*)(qrow2);
    bf8_t b1 = *(const bf8_t*)(qrow2 + 16);
    bf8_t b2 = *(const bf8_t*)(qrow2 + 32);
    f32x16 S0, S1;
#pragma unroll
    for (int r = 0; r < 16; ++r) { S0[r] = 0.f; S1[r] = 0.f; }
    S0 = __builtin_amdgcn_mfma_f32_32x32x16_bf16(a0, b0, S0, 0, 0, 0);
    S0 = __builtin_amdgcn_mfma_f32_32x32x16_bf16(a1, b1, S0, 0, 0, 0);
    S0 = __builtin_amdgcn_mfma_f32_32x32x16_bf16(a2, b2, S0, 0, 0, 0);
    S1 = __builtin_amdgcn_mfma_f32_32x32x16_bf16(a3, b0, S1, 0, 0, 0);
    S1 = __builtin_amdgcn_mfma_f32_32x32x16_bf16(a4, b1, S1, 0, 0, 0);
    S1 = __builtin_amdgcn_mfma_f32_32x32x16_bf16(a5, b2, S1, 0, 0, 0);
#pragma unroll
    for (int r = 0; r < 16; ++r) {
      rs0[r] += exp2fast(S0[r]);
      rs1[r] += exp2fast(S1[r]);
    }
  }
#pragma unroll
  for (int off = 16; off >= 1; off >>= 1)
#pragma unroll
    for (int r = 0; r < 16; ++r) {
      rs0[r] += __shfl_xor(rs0[r], off, 32);
      rs1[r] += __shfl_xor(rs1[r], off, 32);
    }
  if (l31 == 0) {
#pragma unroll
    for (int r = 0; r < 16; ++r) {
      int row = (r & 3) + 8 * (r >> 2) + 4 * h;   // 32x32 C/D row map
      red[wave][row] = rs0[r];
      red[wave][32 + row] = rs1[r];
    }
  }
  __syncthreads();
  if (tid < 64) {
    float s = red[0][tid] + red[1][tid] + red[2][tid] + red[3][tid];
    psum[((size_t)ms * B + b) * N + n0 + tid] = s;
  }
  // last-arriver computes logL for these 64 n and writes kT ch36/37
  __threadfence();
  __syncthreads();
  if (tid == 0) {
    int old = atomicAdd(&cnt[b * 64 + nblk], 1);
    lastflag = (old == MSPLIT - 1);
  }
  __syncthreads();
  if (lastflag && tid < 64) {
    __threadfence();
    float L = psum[(size_t)b * N + n0 + tid] +
              psum[(size_t)(B + b) * N + n0 + tid];
    float t = -__log2f(L);
    unsigned short hi = f2bf(t);
    unsigned short lo = f2bf(t - bf2f(hi));
    size_t base = (bN + n0 + tid) * CP;
    kT[base + 36] = hi;
    kT[base + 37] = lo;
  }
}

// ---------------- Pass 2: staged attn, 2 m-tiles/wave, fused projection ----
__global__ __launch_bounds__(256, 3) void attn_kernel(
    const unsigned short* __restrict__ qT, const unsigned short* __restrict__ kT,
    const unsigned short* __restrict__ vbf, const float* __restrict__ wo,
    float* __restrict__ out) {
  __shared__ unsigned short kbuf[2][32 * 52];     // [n][48+pad4], 104 B rows
  __shared__ unsigned short vbuf[2][48 * 36];     // [c][32+pad4], 72 B rows
  __shared__ unsigned short plds[4][2][32 * 40];  // per-wave 2x P^T [m][n pad40]
  int tid = threadIdx.x, lane = tid & 63, wave = tid >> 6;
  int mblk = blockIdx.x, b = blockIdx.y, z = blockIdx.z;
  int l31 = lane & 31, h = lane >> 5, l15 = lane & 15, q4 = lane >> 4;
  int m0 = mblk * 256 + wave * 64;
  size_t bN = (size_t)b * N;
  // staging: 192 uint4 k-tile + 192 uint4 v-tile per 32-n tile
  bool isK0 = tid < 192;
  int r0row = isK0 ? (tid / 6) : ((tid - 192) >> 2);
  int r0c   = isK0 ? (tid % 6) : ((tid - 192) & 3);
  const unsigned short* s0 = isK0
      ? kT + (bN + z * NCHUNK + r0row) * CP + r0c * 8
      : vbf + ((size_t)b * CP + r0row) * N + z * NCHUNK + r0c * 8;
  int s0stride = isK0 ? 32 * CP : 32;
  unsigned short* dst0 = isK0 ? &kbuf[0][r0row * 52 + r0c * 8]
                              : &vbuf[0][r0row * 36 + r0c * 8];
  int dbs0 = isK0 ? 32 * 52 : 48 * 36;
  bool has1 = tid < 128;                      // second item: v rows 16..47
  int r1row = (tid >> 2) + 16;
  int r1c = tid & 3;
  const unsigned short* s1 =
      vbf + ((size_t)b * CP + r1row) * N + z * NCHUNK + r1c * 8;
  unsigned short* dst1 = &vbuf[0][r1row * 36 + r1c * 8];
  const int dbs1 = 48 * 36;
  // q B-frags for two m-tiles (loop-invariant), incl ch36/37 = 1.0
  bf8_t qb[2][3];
#pragma unroll
  for (int mt = 0; mt < 2; ++mt) {
    const unsigned short* qrow = qT + (bN + m0 + mt * 32 + l31) * CP + h * 8;
    qb[mt][0] = *(const bf8_t*)(qrow);
    qb[mt][1] = *(const bf8_t*)(qrow + 16);
    qb[mt][2] = *(const bf8_t*)(qrow + 32);
  }
  // wo A-frags: A[i=l15][k=16ct+q4*4+j], zero outside 12x36
  bf4_t woa[3];
#pragma unroll
  for (int ct = 0; ct < 3; ++ct) {
    float4 w4 = {0.f, 0.f, 0.f, 0.f};
    int col = 16 * ct + q4 * 4;
    if (l15 < CIN && col < CQ) w4 = *(const float4*)(wo + l15 * CQ + col);
    woa[ct] = bf4_t{(short)f2bf(w4.x), (short)f2bf(w4.y),
                    (short)f2bf(w4.z), (short)f2bf(w4.w)};
  }
  f32x4 acc[2][3][2];
#pragma unroll
  for (int mt = 0; mt < 2; ++mt)
#pragma unroll
    for (int ct = 0; ct < 3; ++ct)
#pragma unroll
      for (int hm = 0; hm < 2; ++hm)
#pragma unroll
        for (int r = 0; r < 4; ++r) acc[mt][ct][hm][r] = 0.f;
  // prologue: stage tile 0
  uint4 r0 = *(const uint4*)s0; s0 += s0stride;
  uint4 r1{0, 0, 0, 0};
  if (has1) { r1 = *(const uint4*)s1; s1 += 32; }
  wlds16(dst0, r0);
  if (has1) wlds16(dst1, r1);
  __syncthreads();
  for (int t = 0; t < NT; ++t) {
    int buf = t & 1;
    if (t + 1 < NT) {                       // prefetch next tile into regs
      r0 = *(const uint4*)s0; s0 += s0stride;
      if (has1) { r1 = *(const uint4*)s1; s1 += 32; }
    }
    const unsigned short* kb = kbuf[buf];
    const unsigned short* vb = vbuf[buf];
    bf8_t a0 = lds_bf8(kb + l31 * 52 + h * 8);
    bf8_t a1 = lds_bf8(kb + l31 * 52 + h * 8 + 16);
    bf8_t a2 = lds_bf8(kb + l31 * 52 + h * 8 + 32);
    bf8_t v0 = lds_bf8(vb + (0 * 16 + l15) * 36 + q4 * 8);
    bf8_t v1 = lds_bf8(vb + (1 * 16 + l15) * 36 + q4 * 8);
    bf8_t v2 = lds_bf8(vb + (2 * 16 + l15) * 36 + q4 * 8);
    // two independent S -> exp -> pack chains
#pragma unroll
    for (int mt = 0; mt < 2; ++mt) {
      f32x16 S;
#pragma unroll
      for (int r = 0; r < 16; ++r) S[r] = 0.f;
      S = __builtin_amdgcn_mfma_f32_32x32x16_bf16(a0, qb[mt][0], S, 0, 0, 0);
      S = __builtin_amdgcn_mfma_f32_32x32x16_bf16(a1, qb[mt][1], S, 0, 0, 0);
      S = __builtin_amdgcn_mfma_f32_32x32x16_bf16(a2, qb[mt][2], S, 0, 0, 0);
      unsigned short* pl = plds[wave][mt];
#pragma unroll
      for (int qd = 0; qd < 4; ++qd) {
        uint2 pk;
        pk.x = pk2bf(exp2fast(S[4 * qd + 0]), exp2fast(S[4 * qd + 1]));
        pk.y = pk2bf(exp2fast(S[4 * qd + 2]), exp2fast(S[4 * qd + 3]));
        *(uint2*)&pl[l31 * 40 + 8 * qd + 4 * h] = pk;
      }
      bf8_t pb0 = *(const bf8_t*)&pl[l15 * 40 + q4 * 8];
      bf8_t pb1 = *(const bf8_t*)&pl[(16 + l15) * 40 + q4 * 8];
      acc[mt][0][0] = __builtin_amdgcn_mfma_f32_16x16x32_bf16(v0, pb0, acc[mt][0][0], 0, 0, 0);
      acc[mt][0][1] = __builtin_amdgcn_mfma_f32_16x16x32_bf16(v0, pb1, acc[mt][0][1], 0, 0, 0);
      acc[mt][1][0] = __builtin_amdgcn_mfma_f32_16x16x32_bf16(v1, pb0, acc[mt][1][0], 0, 0, 0);
      acc[mt][1][1] = __builtin_amdgcn_mfma_f32_16x16x32_bf16(v1, pb1, acc[mt][1][1], 0, 0, 0);
      acc[mt][2][0] = __builtin_amdgcn_mfma_f32_16x16x32_bf16(v2, pb0, acc[mt][2][0], 0, 0, 0);
      acc[mt][2][1] = __builtin_amdgcn_mfma_f32_16x16x32_bf16(v2, pb1, acc[mt][2][1], 0, 0, 0);
    }
    if (t + 1 < NT) {                       // stage next tile into other buf
      int nb = buf ^ 1;
      wlds16(dst0 + nb * dbs0, r0);
      if (has1) wlds16(dst1 + nb * dbs1, r1);
    }
    __syncthreads();
  }
  // fused projection: acc tile (C-layout) == quad-K B-operand layout
#pragma unroll
  for (int mt = 0; mt < 2; ++mt)
#pragma unroll
    for (int hm = 0; hm < 2; ++hm) {
      f32x4 po = {0.f, 0.f, 0.f, 0.f};
#pragma unroll
      for (int ct = 0; ct < 3; ++ct) {
        union { uint2 u; bf4_t v; } pb;
        pb.u.x = pk2bf(acc[mt][ct][hm][0], acc[mt][ct][hm][1]);
        pb.u.y = pk2bf(acc[mt][ct][hm][2], acc[mt][ct][hm][3]);
        po = mfma16(woa[ct], pb.v, po);
      }
      if (q4 < 3) {
        float* ob = out + ((size_t)b * CIN + q4 * 4) * N + m0 + mt * 32 + hm * 16 + l15;
#pragma unroll
        for (int r = 0; r < 4; ++r) atomicAdd(ob + (size_t)r * N, po[r]);
      }
    }
}

extern "C" void kernel_launch(void* const* d_in, const int* in_sizes, int n_in,
                              void* d_out, int out_size, void* d_ws, size_t ws_size,
                              hipStream_t stream) {
  const float* x  = (const float*)d_in[0];
  const float* wq = (const float*)d_in[1];
  const float* bq = (const float*)d_in[2];
  const float* wk = (const float*)d_in[3];
  const float* bk = (const float*)d_in[4];
  const float* wv = (const float*)d_in[5];
  const float* bv = (const float*)d_in[6];
  const float* wo = (const float*)d_in[7];
  const float* bo = (const float*)d_in[8];
  float* out = (float*)d_out;

  char* ws = (char*)d_ws;
  unsigned short* qT  = (unsigned short*)ws;                 // 3,145,728 B
  unsigned short* kT  = (unsigned short*)(ws + 3145728);     // 3,145,728 B
  unsigned short* vbf = (unsigned short*)(ws + 2 * 3145728); // 3,145,728 B
  float* psum = (float*)(ws + 3 * 3145728);                  //   262,144 B
  int* cnt    = (int*)(ws + 3 * 3145728 + 262144);           //     2,048 B

  qkv_kernel<<<dim3(768), 256, 0, stream>>>(x, wq, bq, wk, bk, wv, bv, bo,
                                            qT, kT, vbf, out, cnt);
  stats_kernel<<<dim3(N / 64, B, MSPLIT), 256, 0, stream>>>(qT, kT, psum, cnt);
  attn_kernel<<<dim3(N / 256, B, ZSPLIT), 256, 0, stream>>>(qT, kT, vbf, wo, out);
}

// Round 13
// 136.286 us; speedup vs baseline: 1.5685x; 1.5685x over previous
//
#include <hip/hip_runtime.h>
#include <hip/hip_bf16.h>
#include <math.h>

#define B 8
#define CIN 12
#define CQ 36
#define CP 48               // channel dim padded: 36 data + 2 logL + 10 zero
#define N 4096
#define SCALE 0.28867513459481287f   // 1/sqrt(12)
#define LOG2E 1.4426950408889634f
#define ZSPLIT 8
#define NCHUNK (N / ZSPLIT) // 512
#define NT (NCHUNK / 32)    // 16 tiles per attn WG
#define MSPLIT 4

typedef __attribute__((ext_vector_type(4)))  short bf4_t;
typedef __attribute__((ext_vector_type(8)))  short bf8_t;
typedef __attribute__((ext_vector_type(16))) float f32x16;
typedef __attribute__((ext_vector_type(4)))  float f32x4;

__device__ __forceinline__ unsigned short f2bf(float x) {
  unsigned int u = __float_as_uint(x);
  u += 0x7FFFu + ((u >> 16) & 1u);   // RNE
  return (unsigned short)(u >> 16);
}

#if __has_builtin(__builtin_amdgcn_cvt_pk_bf16_f32)
typedef __attribute__((ext_vector_type(2))) __bf16 bf16x2_t;
__device__ __forceinline__ unsigned pk2bf(float a, float b) {
  bf16x2_t v = __builtin_amdgcn_cvt_pk_bf16_f32(a, b);
  return __builtin_bit_cast(unsigned, v);
}
#else
__device__ __forceinline__ unsigned pk2bf(float a, float b) {
  return (__float_as_uint(a) >> 16) | (__float_as_uint(b) & 0xFFFF0000u);
}
#endif

__device__ __forceinline__ float bf2f(unsigned short u) {
  return __uint_as_float((unsigned)u << 16);
}

__device__ __forceinline__ float exp2fast(float x) {
#if __has_builtin(__builtin_amdgcn_exp2f)
  return __builtin_amdgcn_exp2f(x);
#else
  return exp2f(x);
#endif
}

// 16x16x16 quad-K MFMA (verified R4-R8): A[m=l15][k=q4*4+i], B[k][n=l15],
// D col=l15 row=q4*4+r.
__device__ __forceinline__ f32x4 mfma16(bf4_t a, bf4_t b, f32x4 c) {
#if __has_builtin(__builtin_amdgcn_mfma_f32_16x16x16bf16_1k)
  return __builtin_amdgcn_mfma_f32_16x16x16bf16_1k(a, b, c, 0, 0, 0);
#else
  bf8_t a8 = {a[0], a[1], a[2], a[3], 0, 0, 0, 0};
  bf8_t b8 = {b[0], b[1], b[2], b[3], 0, 0, 0, 0};
  return __builtin_amdgcn_mfma_f32_16x16x32_bf16(a8, b8, c, 0, 0, 0);
#endif
}

// 16B LDS access helpers for 8B-aligned addresses (rows padded to 104/72 B)
__device__ __forceinline__ bf8_t lds_bf8(const unsigned short* p) {
  uint2 a = *(const uint2*)p;
  uint2 b = *(const uint2*)(p + 4);
  uint4 r{a.x, a.y, b.x, b.y};
  return __builtin_bit_cast(bf8_t, r);
}
__device__ __forceinline__ void wlds16(unsigned short* p, uint4 v) {
  *(uint2*)p = uint2{v.x, v.y};
  *(uint2*)(p + 4) = uint2{v.z, v.w};
}

// ---------------- QKV projection + out-bias-init ---------------------------
// 1-D grid 768: [0,128) q, [128,256) k(scaled), [256,384) v, [384,768) init.
__global__ __launch_bounds__(256) void qkv_kernel(
    const float* __restrict__ x,
    const float* __restrict__ wq, const float* __restrict__ bq,
    const float* __restrict__ wk, const float* __restrict__ bk,
    const float* __restrict__ wv, const float* __restrict__ bv,
    const float* __restrict__ bo,
    unsigned short* __restrict__ qT, unsigned short* __restrict__ kT,
    unsigned short* __restrict__ vbf, float* __restrict__ out) {
  __shared__ float sw[CQ * CIN];
  __shared__ float sb[CQ];
  int bx = blockIdx.x, tid = threadIdx.x;
  int role = bx >> 7; if (role > 3) role = 3;
  if (role == 3) {
    int gid = (bx - 384) * 256 + tid;   // over B*CIN*N/4
    int e4 = gid * 4;
    int i = (e4 >> 12) % CIN;
    float bv2 = bo[i];
    *(float4*)(out + e4) = float4{bv2, bv2, bv2, bv2};
    return;
  }
  const float* w  = (role == 0) ? wq : (role == 1) ? wk : wv;
  const float* bb = (role == 0) ? bq : (role == 1) ? bk : bv;
  float scale = (role == 1) ? SCALE * LOG2E : 1.0f;
  for (int e = tid; e < CQ * CIN; e += 256) sw[e] = w[e] * scale;
  if (tid < CQ) sb[tid] = bb[tid] * scale;
  __syncthreads();
  int gid = (bx & 127) * 256 + tid;    // over B*N
  int b = gid >> 12;
  int n = gid & (N - 1);
  float xv[CIN];
#pragma unroll
  for (int i = 0; i < CIN; ++i) xv[i] = x[(b * CIN + i) * N + n];
  if (role == 2) {
#pragma unroll
    for (int o = 0; o < CQ; ++o) {
      float a = sb[o];
#pragma unroll
      for (int i = 0; i < CIN; ++i) a += sw[o * CIN + i] * xv[i];
      vbf[((size_t)b * CP + o) * N + n] = f2bf(a);
    }
  } else {
    __attribute__((aligned(16))) unsigned row[CP / 2];
#pragma unroll
    for (int o = 0; o < CQ; o += 2) {
      float a0 = sb[o], a1 = sb[o + 1];
#pragma unroll
      for (int i = 0; i < CIN; ++i) {
        float xi = xv[i];
        a0 += sw[o * CIN + i] * xi;
        a1 += sw[(o + 1) * CIN + i] * xi;
      }
      row[o / 2] = (unsigned)f2bf(a0) | ((unsigned)f2bf(a1) << 16);
    }
    row[18] = (role == 0) ? 0x3F803F80u : 0u;  // q ch36/37=1.0; k: prep fills
#pragma unroll
    for (int o = 19; o < CP / 2; ++o) row[o] = 0;
    unsigned short* dst = ((role == 0) ? qT : kT) + ((size_t)b * N + n) * CP;
#pragma unroll
    for (int i = 0; i < 6; ++i) *(uint4*)(dst + 8 * i) = *(const uint4*)&row[4 * i];
  }
}

// ---------------- Pass 1: psum[ms][b][n], 2 n-blocks per wave --------------
__global__ __launch_bounds__(256) void stats_kernel(
    const unsigned short* __restrict__ qT, const unsigned short* __restrict__ kT,
    float* __restrict__ psum) {
  __shared__ float red[4][64];
  int tid = threadIdx.x, lane = tid & 63, wave = tid >> 6;
  int nblk = blockIdx.x, b = blockIdx.y, ms = blockIdx.z;
  int l31 = lane & 31, h = lane >> 5;
  int n0 = nblk * 64;
  size_t bN = (size_t)b * N;
  const unsigned short* krow0 = kT + (bN + n0 + l31) * CP + h * 8;
  const unsigned short* krow1 = krow0 + (size_t)32 * CP;
  bf8_t a0 = *(const bf8_t*)(krow0);
  bf8_t a1 = *(const bf8_t*)(krow0 + 16);
  bf8_t a2 = *(const bf8_t*)(krow0 + 32);
  bf8_t a3 = *(const bf8_t*)(krow1);
  bf8_t a4 = *(const bf8_t*)(krow1 + 16);
  bf8_t a5 = *(const bf8_t*)(krow1 + 32);
  float rs0[16], rs1[16];
#pragma unroll
  for (int r = 0; r < 16; ++r) { rs0[r] = 0.f; rs1[r] = 0.f; }
  const int MW = N / MSPLIT / 4;   // 256 m per wave
  const unsigned short* qbase =
      qT + (bN + ms * (N / MSPLIT) + wave * MW + l31) * CP + h * 8;
#pragma unroll 2
  for (int t = 0; t < MW / 32; ++t) {
    const unsigned short* qrow2 = qbase + (size_t)t * 32 * CP;
    bf8_t b0 = *(const bf8_t*)(qrow2);
    bf8_t b1 = *(const bf8_t*)(qrow2 + 16);
    bf8_t b2 = *(const bf8_t*)(qrow2 + 32);
    f32x16 S0, S1;
#pragma unroll
    for (int r = 0; r < 16; ++r) { S0[r] = 0.f; S1[r] = 0.f; }
    S0 = __builtin_amdgcn_mfma_f32_32x32x16_bf16(a0, b0, S0, 0, 0, 0);
    S0 = __builtin_amdgcn_mfma_f32_32x32x16_bf16(a1, b1, S0, 0, 0, 0);
    S0 = __builtin_amdgcn_mfma_f32_32x32x16_bf16(a2, b2, S0, 0, 0, 0);
    S1 = __builtin_amdgcn_mfma_f32_32x32x16_bf16(a3, b0, S1, 0, 0, 0);
    S1 = __builtin_amdgcn_mfma_f32_32x32x16_bf16(a4, b1, S1, 0, 0, 0);
    S1 = __builtin_amdgcn_mfma_f32_32x32x16_bf16(a5, b2, S1, 0, 0, 0);
#pragma unroll
    for (int r = 0; r < 16; ++r) {
      rs0[r] += exp2fast(S0[r]);
      rs1[r] += exp2fast(S1[r]);
    }
  }
#pragma unroll
  for (int off = 16; off >= 1; off >>= 1)
#pragma unroll
    for (int r = 0; r < 16; ++r) {
      rs0[r] += __shfl_xor(rs0[r], off, 32);
      rs1[r] += __shfl_xor(rs1[r], off, 32);
    }
  if (l31 == 0) {
#pragma unroll
    for (int r = 0; r < 16; ++r) {
      int row = (r & 3) + 8 * (r >> 2) + 4 * h;   // 32x32 C/D row map
      red[wave][row] = rs0[r];
      red[wave][32 + row] = rs1[r];
    }
  }
  __syncthreads();
  if (tid < 64) {
    float s = red[0][tid] + red[1][tid] + red[2][tid] + red[3][tid];
    psum[((size_t)ms * B + b) * N + n0 + tid] = s;
  }
}

// ---------------- prep: finalize logL into kT ch36/37 ----------------------
__global__ __launch_bounds__(256) void prep_kernel(
    const float* __restrict__ psum, unsigned short* __restrict__ kT) {
  int gid = blockIdx.x * 256 + threadIdx.x;   // = b*N + n
  float L = 0.f;
#pragma unroll
  for (int ms = 0; ms < MSPLIT; ++ms) L += psum[(size_t)ms * B * N + gid];
  float t = -__log2f(L);
  unsigned short hi = f2bf(t);
  unsigned short lo = f2bf(t - bf2f(hi));
  size_t base = (size_t)gid * CP;
  kT[base + 36] = hi;
  kT[base + 37] = lo;
}

// ---------------- Pass 2: staged attn, 2 m-tiles/wave, fused projection ----
__global__ __launch_bounds__(256, 3) void attn_kernel(
    const unsigned short* __restrict__ qT, const unsigned short* __restrict__ kT,
    const unsigned short* __restrict__ vbf, const float* __restrict__ wo,
    float* __restrict__ out) {
  __shared__ unsigned short kbuf[2][32 * 52];     // [n][48+pad4], 104 B rows
  __shared__ unsigned short vbuf[2][48 * 36];     // [c][32+pad4], 72 B rows
  __shared__ unsigned short plds[4][2][32 * 40];  // per-wave 2x P^T [m][n pad40]
  int tid = threadIdx.x, lane = tid & 63, wave = tid >> 6;
  int mblk = blockIdx.x, b = blockIdx.y, z = blockIdx.z;
  int l31 = lane & 31, h = lane >> 5, l15 = lane & 15, q4 = lane >> 4;
  int m0 = mblk * 256 + wave * 64;
  size_t bN = (size_t)b * N;
  // staging: 192 uint4 k-tile + 192 uint4 v-tile per 32-n tile
  bool isK0 = tid < 192;
  int r0row = isK0 ? (tid / 6) : ((tid - 192) >> 2);
  int r0c   = isK0 ? (tid % 6) : ((tid - 192) & 3);
  const unsigned short* s0 = isK0
      ? kT + (bN + z * NCHUNK + r0row) * CP + r0c * 8
      : vbf + ((size_t)b * CP + r0row) * N + z * NCHUNK + r0c * 8;
  int s0stride = isK0 ? 32 * CP : 32;
  unsigned short* dst0 = isK0 ? &kbuf[0][r0row * 52 + r0c * 8]
                              : &vbuf[0][r0row * 36 + r0c * 8];
  int dbs0 = isK0 ? 32 * 52 : 48 * 36;
  bool has1 = tid < 128;                      // second item: v rows 16..47
  int r1row = (tid >> 2) + 16;
  int r1c = tid & 3;
  const unsigned short* s1 =
      vbf + ((size_t)b * CP + r1row) * N + z * NCHUNK + r1c * 8;
  unsigned short* dst1 = &vbuf[0][r1row * 36 + r1c * 8];
  const int dbs1 = 48 * 36;
  // q B-frags for two m-tiles (loop-invariant), incl ch36/37 = 1.0
  bf8_t qb[2][3];
#pragma unroll
  for (int mt = 0; mt < 2; ++mt) {
    const unsigned short* qrow = qT + (bN + m0 + mt * 32 + l31) * CP + h * 8;
    qb[mt][0] = *(const bf8_t*)(qrow);
    qb[mt][1] = *(const bf8_t*)(qrow + 16);
    qb[mt][2] = *(const bf8_t*)(qrow + 32);
  }
  // wo A-frags: A[i=l15][k=16ct+q4*4+j], zero outside 12x36
  bf4_t woa[3];
#pragma unroll
  for (int ct = 0; ct < 3; ++ct) {
    float4 w4 = {0.f, 0.f, 0.f, 0.f};
    int col = 16 * ct + q4 * 4;
    if (l15 < CIN && col < CQ) w4 = *(const float4*)(wo + l15 * CQ + col);
    woa[ct] = bf4_t{(short)f2bf(w4.x), (short)f2bf(w4.y),
                    (short)f2bf(w4.z), (short)f2bf(w4.w)};
  }
  f32x4 acc[2][3][2];
#pragma unroll
  for (int mt = 0; mt < 2; ++mt)
#pragma unroll
    for (int ct = 0; ct < 3; ++ct)
#pragma unroll
      for (int hm = 0; hm < 2; ++hm)
#pragma unroll
        for (int r = 0; r < 4; ++r) acc[mt][ct][hm][r] = 0.f;
  // prologue: stage tile 0
  uint4 r0 = *(const uint4*)s0; s0 += s0stride;
  uint4 r1{0, 0, 0, 0};
  if (has1) { r1 = *(const uint4*)s1; s1 += 32; }
  wlds16(dst0, r0);
  if (has1) wlds16(dst1, r1);
  __syncthreads();
  for (int t = 0; t < NT; ++t) {
    int buf = t & 1;
    if (t + 1 < NT) {                       // prefetch next tile into regs
      r0 = *(const uint4*)s0; s0 += s0stride;
      if (has1) { r1 = *(const uint4*)s1; s1 += 32; }
    }
    const unsigned short* kb = kbuf[buf];
    const unsigned short* vb = vbuf[buf];
    bf8_t a0 = lds_bf8(kb + l31 * 52 + h * 8);
    bf8_t a1 = lds_bf8(kb + l31 * 52 + h * 8 + 16);
    bf8_t a2 = lds_bf8(kb + l31 * 52 + h * 8 + 32);
    bf8_t v0 = lds_bf8(vb + (0 * 16 + l15) * 36 + q4 * 8);
    bf8_t v1 = lds_bf8(vb + (1 * 16 + l15) * 36 + q4 * 8);
    bf8_t v2 = lds_bf8(vb + (2 * 16 + l15) * 36 + q4 * 8);
    // two independent S -> exp -> pack chains
#pragma unroll
    for (int mt = 0; mt < 2; ++mt) {
      f32x16 S;
#pragma unroll
      for (int r = 0; r < 16; ++r) S[r] = 0.f;
      S = __builtin_amdgcn_mfma_f32_32x32x16_bf16(a0, qb[mt][0], S, 0, 0, 0);
      S = __builtin_amdgcn_mfma_f32_32x32x16_bf16(a1, qb[mt][1], S, 0, 0, 0);
      S = __builtin_amdgcn_mfma_f32_32x32x16_bf16(a2, qb[mt][2], S, 0, 0, 0);
      unsigned short* pl = plds[wave][mt];
#pragma unroll
      for (int qd = 0; qd < 4; ++qd) {
        uint2 pk;
        pk.x = pk2bf(exp2fast(S[4 * qd + 0]), exp2fast(S[4 * qd + 1]));
        pk.y = pk2bf(exp2fast(S[4 * qd + 2]), exp2fast(S[4 * qd + 3]));
        *(uint2*)&pl[l31 * 40 + 8 * qd + 4 * h] = pk;
      }
      bf8_t pb0 = *(const bf8_t*)&pl[l15 * 40 + q4 * 8];
      bf8_t pb1 = *(const bf8_t*)&pl[(16 + l15) * 40 + q4 * 8];
      acc[mt][0][0] = __builtin_amdgcn_mfma_f32_16x16x32_bf16(v0, pb0, acc[mt][0][0], 0, 0, 0);
      acc[mt][0][1] = __builtin_amdgcn_mfma_f32_16x16x32_bf16(v0, pb1, acc[mt][0][1], 0, 0, 0);
      acc[mt][1][0] = __builtin_amdgcn_mfma_f32_16x16x32_bf16(v1, pb0, acc[mt][1][0], 0, 0, 0);
      acc[mt][1][1] = __builtin_amdgcn_mfma_f32_16x16x32_bf16(v1, pb1, acc[mt][1][1], 0, 0, 0);
      acc[mt][2][0] = __builtin_amdgcn_mfma_f32_16x16x32_bf16(v2, pb0, acc[mt][2][0], 0, 0, 0);
      acc[mt][2][1] = __builtin_amdgcn_mfma_f32_16x16x32_bf16(v2, pb1, acc[mt][2][1], 0, 0, 0);
    }
    if (t + 1 < NT) {                       // stage next tile into other buf
      int nb = buf ^ 1;
      wlds16(dst0 + nb * dbs0, r0);
      if (has1) wlds16(dst1 + nb * dbs1, r1);
    }
    __syncthreads();
  }
  // fused projection: acc tile (C-layout) == quad-K B-operand layout
#pragma unroll
  for (int mt = 0; mt < 2; ++mt)
#pragma unroll
    for (int hm = 0; hm < 2; ++hm) {
      f32x4 po = {0.f, 0.f, 0.f, 0.f};
#pragma unroll
      for (int ct = 0; ct < 3; ++ct) {
        union { uint2 u; bf4_t v; } pb;
        pb.u.x = pk2bf(acc[mt][ct][hm][0], acc[mt][ct][hm][1]);
        pb.u.y = pk2bf(acc[mt][ct][hm][2], acc[mt][ct][hm][3]);
        po = mfma16(woa[ct], pb.v, po);
      }
      if (q4 < 3) {
        float* ob = out + ((size_t)b * CIN + q4 * 4) * N + m0 + mt * 32 + hm * 16 + l15;
#pragma unroll
        for (int r = 0; r < 4; ++r) atomicAdd(ob + (size_t)r * N, po[r]);
      }
    }
}

extern "C" void kernel_launch(void* const* d_in, const int* in_sizes, int n_in,
                              void* d_out, int out_size, void* d_ws, size_t ws_size,
                              hipStream_t stream) {
  const float* x  = (const float*)d_in[0];
  const float* wq = (const float*)d_in[1];
  const float* bq = (const float*)d_in[2];
  const float* wk = (const float*)d_in[3];
  const float* bk = (const float*)d_in[4];
  const float* wv = (const float*)d_in[5];
  const float* bv = (const float*)d_in[6];
  const float* wo = (const float*)d_in[7];
  const float* bo = (const float*)d_in[8];
  float* out = (float*)d_out;

  char* ws = (char*)d_ws;
  unsigned short* qT  = (unsigned short*)ws;                 // 3,145,728 B
  unsigned short* kT  = (unsigned short*)(ws + 3145728);     // 3,145,728 B
  unsigned short* vbf = (unsigned short*)(ws + 2 * 3145728); // 3,145,728 B
  float* psum = (float*)(ws + 3 * 3145728);                  //   524,288 B

  qkv_kernel<<<dim3(768), 256, 0, stream>>>(x, wq, bq, wk, bk, wv, bv, bo,
                                            qT, kT, vbf, out);
  stats_kernel<<<dim3(N / 64, B, MSPLIT), 256, 0, stream>>>(qT, kT, psum);
  prep_kernel<<<dim3(B * N / 256), 256, 0, stream>>>(psum, kT);
  attn_kernel<<<dim3(N / 256, B, ZSPLIT), 256, 0, stream>>>(qT, kT, vbf, wo, out);
}